// Round 1
// baseline (68191.742 us; speedup 1.0000x reference)
//
#include <hip/hip_runtime.h>

// BasicGRU persistent kernel for MI355X (gfx950).
//
// Design (round 1):
//  - Persistent kernel: 256 wgs x 256 threads, 1 wg/CU (forced by ~101KB LDS).
//  - 4 independent groups by batch-block of 16 rows (GRU rows are independent);
//    each group = 64 wgs, synced by a monotonic-counter atomic barrier in d_ws,
//    2 barriers per time step (phase1: z/r/zt + hr; phase2: u -> h update).
//  - Weights resident in LDS as bf16 hi/lo split (loaded once before the loop).
//    Recurrent GEMMs via mfma_f32_16x16x32_bf16, 3 products (hh, hl, lh) for
//    ~fp32 accuracy (split error ~1.5e-5 rel << 1.88e-2 threshold).
//  - A-operand: x slice loaded fp32 + split on the fly; h / (h*r) stored in ws
//    as pre-split bf16 hi/lo pairs by the producing phase.
//  - K=768 (256 x-part + 512 h-part) split over the 4 waves; partial C tiles
//    reduced via LDS scratch.
//
// ws layout (bytes):
//   0        h_f32   [64][512] f32
//   131072   zt_f32  [64][512] f32
//   262144   h_hi    [64][512] bf16
//   327680   h_lo    [64][512] bf16
//   393216   hr_hi   [64][512] bf16
//   458752   hr_lo   [64][512] bf16
//   524288   barrier counters (4 groups, 256B apart)
//   total 525312 (memset to 0 at each launch -> h0 = 0, counters = 0)

#define BB 64
#define TT 2048
#define DD 256
#define UU 512
#define K1 (DD + UU)   // 768
#define WPAD 776       // padded LDS k-stride (bf16 elems) to break bank conflicts

typedef short bf16x8 __attribute__((ext_vector_type(8)));
typedef float f32x4 __attribute__((ext_vector_type(4)));

__device__ inline unsigned short f2bf(float f) {
  unsigned u = __builtin_bit_cast(unsigned, f);
  u += 0x7FFFu + ((u >> 16) & 1u);          // round-nearest-even
  return (unsigned short)(u >> 16);
}
__device__ inline float bf2f(unsigned short b) {
  unsigned u = ((unsigned)b) << 16;
  return __builtin_bit_cast(float, u);
}

__device__ inline void group_barrier(unsigned* ctr, unsigned target) {
  __syncthreads();
  if (threadIdx.x == 0) {
    __threadfence();  // release our wg's prior global stores (agent scope)
    __hip_atomic_fetch_add(ctr, 1u, __ATOMIC_RELAXED, __HIP_MEMORY_SCOPE_AGENT);
    unsigned v;
    do {
      __builtin_amdgcn_s_sleep(1);
      v = __hip_atomic_load(ctr, __ATOMIC_ACQUIRE, __HIP_MEMORY_SCOPE_AGENT);
    } while (v < target);
  }
  __syncthreads();
}

// One 16x16 output tile's K-partial for this wave: K slice [wv*192, wv*192+192).
// A = [x_t fp32 (k<256, split on the fly) | v (k>=256, pre-split bf16 hi/lo)]
// B = LDS weights, layout [c][WPAD] bf16 (transposed, k contiguous).
__device__ inline f32x4 tile_gemm(const unsigned short* __restrict__ whi_lds,
                                  const unsigned short* __restrict__ wlo_lds,
                                  const unsigned short* __restrict__ vhi,
                                  const unsigned short* __restrict__ vlo,
                                  const float* __restrict__ xrow,
                                  int rowb, int wv, int lane) {
  f32x4 acc = {0.f, 0.f, 0.f, 0.f};
  const int kgrp = lane >> 4;   // 0..3
  const int c = lane & 15;      // tile column
#pragma unroll
  for (int ch = 0; ch < 6; ++ch) {
    const int kbase = wv * 192 + ch * 32;
    const int koff = kbase + kgrp * 8;
    bf16x8 ahi, alo;
    if (kbase < DD) {  // x part (chunk never straddles the 256 boundary)
      f32x4 v0 = *(const f32x4*)(xrow + koff);
      f32x4 v1 = *(const f32x4*)(xrow + koff + 4);
#pragma unroll
      for (int i = 0; i < 4; ++i) {
        unsigned short hb = f2bf(v0[i]);
        ahi[i] = (short)hb;
        alo[i] = (short)f2bf(v0[i] - bf2f(hb));
        unsigned short hb2 = f2bf(v1[i]);
        ahi[4 + i] = (short)hb2;
        alo[4 + i] = (short)f2bf(v1[i] - bf2f(hb2));
      }
    } else {           // h / hr part: pre-split bf16 pairs in ws
      const int k0 = koff - DD;
      ahi = *(const bf16x8*)(vhi + (size_t)rowb * UU + k0);
      alo = *(const bf16x8*)(vlo + (size_t)rowb * UU + k0);
    }
    bf16x8 bhi = *(const bf16x8*)(whi_lds + c * WPAD + koff);
    bf16x8 blo = *(const bf16x8*)(wlo_lds + c * WPAD + koff);
    acc = __builtin_amdgcn_mfma_f32_16x16x32_bf16(ahi, bhi, acc, 0, 0, 0);
    acc = __builtin_amdgcn_mfma_f32_16x16x32_bf16(ahi, blo, acc, 0, 0, 0);
    acc = __builtin_amdgcn_mfma_f32_16x16x32_bf16(alo, bhi, acc, 0, 0, 0);
  }
  return acc;
}

__global__ __launch_bounds__(256, 1) void gru_persist(
    const float* __restrict__ x, const float* __restrict__ Wk,
    const float* __restrict__ Wrk, const float* __restrict__ brk,
    const float* __restrict__ Wu, const float* __restrict__ Wur,
    const float* __restrict__ bur, float* __restrict__ out,
    unsigned char* __restrict__ ws) {
  __shared__ unsigned short w1hi[16 * WPAD], w1lo[16 * WPAD];
  __shared__ unsigned short w2hi[16 * WPAD], w2lo[16 * WPAD];
  __shared__ float scratch[4 * 256];

  const int wg = blockIdx.x;
  const int bblk = wg & 3;        // batch block (16 rows)
  const int cblk = wg >> 2;       // 0..63: z cols [cblk*16, +16); if <32 also u cols
  const int tid = threadIdx.x;
  const int lane = tid & 63;
  const int wv = tid >> 6;

  float* h_f32 = (float*)(ws);
  float* zt_f32 = (float*)(ws + 131072);
  unsigned short* h_hi = (unsigned short*)(ws + 262144);
  unsigned short* h_lo = (unsigned short*)(ws + 327680);
  unsigned short* hr_hi = (unsigned short*)(ws + 393216);
  unsigned short* hr_lo = (unsigned short*)(ws + 458752);
  unsigned* ctr = (unsigned*)(ws + 524288) + (size_t)bblk * 64;

  const int C0 = cblk * 16;

  // ---- one-time weight preload into LDS (bf16 hi/lo split, transposed [c][k])
  for (int idx = tid; idx < 16 * K1; idx += 256) {
    int c = idx & 15, k = idx >> 4;
    float v = (k < DD) ? Wk[(size_t)k * 1024 + C0 + c]
                       : Wrk[(size_t)(k - DD) * 1024 + C0 + c];
    unsigned short hb = f2bf(v);
    w1hi[c * WPAD + k] = hb;
    w1lo[c * WPAD + k] = f2bf(v - bf2f(hb));
  }
  if (cblk < 32) {
    for (int idx = tid; idx < 16 * K1; idx += 256) {
      int c = idx & 15, k = idx >> 4;
      float v = (k < DD) ? Wu[(size_t)k * UU + C0 + c]
                         : Wur[(size_t)(k - DD) * UU + C0 + c];
      unsigned short hb = f2bf(v);
      w2hi[c * WPAD + k] = hb;
      w2lo[c * WPAD + k] = f2bf(v - bf2f(hb));
    }
  }
  __syncthreads();

  const int rowb = bblk * 16 + (lane & 15);  // this lane's global batch row
  unsigned bar = 0;

  for (int t = 0; t < TT; ++t) {
    const float* xrow = x + (size_t)rowb * TT * DD + (size_t)t * DD;

    // ---------- phase 1: z tile [16 x 16] for cols C0..C0+15 of 1024
    {
      f32x4 a = tile_gemm(w1hi, w1lo, h_hi, h_lo, xrow, rowb, wv, lane);
#pragma unroll
      for (int r = 0; r < 4; ++r)
        scratch[wv * 256 + ((lane >> 4) * 4 + r) * 16 + (lane & 15)] = a[r];
      __syncthreads();
      {
        int bl = tid >> 4, cl = tid & 15;
        float z = scratch[tid] + scratch[256 + tid] + scratch[512 + tid] +
                  scratch[768 + tid];
        int Cg = C0 + cl;
        int B = bblk * 16 + bl;
        z += brk[Cg];
        float s = 1.f / (1.f + expf(-z));
        if (Cg < UU) {  // r gate -> h*r, split to bf16 pair
          float hrv = h_f32[(size_t)B * UU + Cg] * s;
          unsigned short hb = f2bf(hrv);
          hr_hi[(size_t)B * UU + Cg] = hb;
          hr_lo[(size_t)B * UU + Cg] = f2bf(hrv - bf2f(hb));
        } else {        // update gate
          zt_f32[(size_t)B * UU + (Cg - UU)] = s;
        }
      }
    }
    group_barrier(ctr, (++bar) * 64);

    // ---------- phase 2: u tile -> h update (wgs with cblk < 32)
    if (cblk < 32) {
      f32x4 a = tile_gemm(w2hi, w2lo, hr_hi, hr_lo, xrow, rowb, wv, lane);
#pragma unroll
      for (int r = 0; r < 4; ++r)
        scratch[wv * 256 + ((lane >> 4) * 4 + r) * 16 + (lane & 15)] = a[r];
      __syncthreads();
      {
        int bl = tid >> 4, cl = tid & 15;
        float u = scratch[tid] + scratch[256 + tid] + scratch[512 + tid] +
                  scratch[768 + tid];
        int Cu = C0 + cl;
        int B = bblk * 16 + bl;
        u += bur[Cu];
        float ht = tanhf(u);
        float zt = zt_f32[(size_t)B * UU + Cu];
        float ho = h_f32[(size_t)B * UU + Cu];
        float hn = ho + zt * (ht - ho);
        h_f32[(size_t)B * UU + Cu] = hn;
        unsigned short hb = f2bf(hn);
        h_hi[(size_t)B * UU + Cu] = hb;
        h_lo[(size_t)B * UU + Cu] = f2bf(hn - bf2f(hb));
        if (t == TT - 1) out[(size_t)B * UU + Cu] = hn;
      }
    }
    group_barrier(ctr, (++bar) * 64);
  }
}

extern "C" void kernel_launch(void* const* d_in, const int* in_sizes, int n_in,
                              void* d_out, int out_size, void* d_ws,
                              size_t ws_size, hipStream_t stream) {
  (void)in_sizes; (void)n_in; (void)out_size; (void)ws_size;
  // zero h state + barrier counters (graph-capturable async memset)
  hipMemsetAsync(d_ws, 0, 525312, stream);
  gru_persist<<<dim3(256), dim3(256), 0, stream>>>(
      (const float*)d_in[0], (const float*)d_in[1], (const float*)d_in[2],
      (const float*)d_in[3], (const float*)d_in[4], (const float*)d_in[5],
      (const float*)d_in[6], (float*)d_out, (unsigned char*)d_ws);
}

// Round 2
// 23884.416 us; speedup vs baseline: 2.8551x; 2.8551x over previous
//
#include <hip/hip_runtime.h>

// BasicGRU persistent kernel for MI355X (gfx950) — round 2.
//
// Change vs round 1: all cross-workgroup traffic (h, h*r, z-gate, barrier
// counters) goes through RELAXED agent-scope atomics (global_load/store with
// sc0 sc1 — coherent at L3, bypassing non-coherent L1/L2). No
// __threadfence / ACQUIRE anywhere in the loop -> no buffer_wbl2 / buffer_inv
// cache maintenance, which was ~16us per barrier phase in round 1.
// Barrier ordering: __syncthreads lowers to s_waitcnt vmcnt(0)+s_barrier, so
// every wave's coherent stores are at the coherence point before the leader's
// relaxed atomic_add; consumers poll the counter with relaxed loads and then
// read data with coherent loads.
//
// h and h*r are stored packed: u32 = (bf16_hi << 16) | bf16_lo per element
// (hi/lo split of fp32 for 3-product MFMA emulation, split err ~1.5e-5 rel).
//
// ws layout (bytes):
//   0        zt_f32   [64][512] f32   (update gate, per step)
//   131072   h_pack   [64][512] u32   (hi<<16|lo)
//   262144   hr_pack  [64][512] u32
//   393216   barrier counters (4 groups, 256B apart)
//   total 394240, memset to 0 each launch (h0 = 0, counters = 0).

#define BB 64
#define TT 2048
#define DD 256
#define UU 512
#define K1 (DD + UU)   // 768
#define WPAD 776       // padded LDS k-stride (bf16 elems)

typedef short bf16x8 __attribute__((ext_vector_type(8)));
typedef float f32x4 __attribute__((ext_vector_type(4)));
typedef unsigned int u32;
typedef unsigned long long u64;

__device__ inline unsigned short f2bf(float f) {
  unsigned u = __builtin_bit_cast(unsigned, f);
  u += 0x7FFFu + ((u >> 16) & 1u);          // round-nearest-even
  return (unsigned short)(u >> 16);
}
__device__ inline float bf2f(unsigned short b) {
  unsigned u = ((unsigned)b) << 16;
  return __builtin_bit_cast(float, u);
}

__device__ inline u32 ld_coh_u32(const u32* p) {
  return __hip_atomic_load(p, __ATOMIC_RELAXED, __HIP_MEMORY_SCOPE_AGENT);
}
__device__ inline u64 ld_coh_u64(const u64* p) {
  return __hip_atomic_load(p, __ATOMIC_RELAXED, __HIP_MEMORY_SCOPE_AGENT);
}
__device__ inline float ld_coh_f32(const float* p) {
  return __hip_atomic_load(p, __ATOMIC_RELAXED, __HIP_MEMORY_SCOPE_AGENT);
}
__device__ inline void st_coh_u32(u32* p, u32 v) {
  __hip_atomic_store(p, v, __ATOMIC_RELAXED, __HIP_MEMORY_SCOPE_AGENT);
}
__device__ inline void st_coh_f32(float* p, float v) {
  __hip_atomic_store(p, v, __ATOMIC_RELAXED, __HIP_MEMORY_SCOPE_AGENT);
}

// No cache-maintenance barrier: data is coherent by construction (sc0 sc1).
__device__ inline void group_barrier(unsigned* ctr, unsigned target) {
  asm volatile("s_waitcnt vmcnt(0)" ::: "memory");  // belt & braces: drain own stores
  __syncthreads();
  if (threadIdx.x == 0) {
    __hip_atomic_fetch_add(ctr, 1u, __ATOMIC_RELAXED, __HIP_MEMORY_SCOPE_AGENT);
    while (__hip_atomic_load(ctr, __ATOMIC_RELAXED, __HIP_MEMORY_SCOPE_AGENT) <
           target)
      __builtin_amdgcn_s_sleep(1);
  }
  __syncthreads();
}

// One 16x16 output tile's K-partial for this wave: K slice [wv*192, +192).
// A = [x_t fp32 (k<256, split on the fly) | packed hi/lo (k>=256, coherent)]
// B = LDS weights, layout [c][WPAD] bf16 (transposed, k contiguous).
__device__ inline f32x4 tile_gemm(const unsigned short* __restrict__ whi_lds,
                                  const unsigned short* __restrict__ wlo_lds,
                                  const u32* __restrict__ vpack,
                                  const float* __restrict__ xrow,
                                  int rowb, int wv, int lane) {
  f32x4 acc = {0.f, 0.f, 0.f, 0.f};
  const int kgrp = lane >> 4;   // 0..3
  const int c = lane & 15;      // tile column
#pragma unroll
  for (int ch = 0; ch < 6; ++ch) {
    const int kbase = wv * 192 + ch * 32;
    const int koff = kbase + kgrp * 8;
    bf16x8 ahi, alo;
    if (kbase < DD) {  // x part (chunk never straddles the 256 boundary)
      f32x4 v0 = *(const f32x4*)(xrow + koff);
      f32x4 v1 = *(const f32x4*)(xrow + koff + 4);
#pragma unroll
      for (int i = 0; i < 4; ++i) {
        unsigned short hb = f2bf(v0[i]);
        ahi[i] = (short)hb;
        alo[i] = (short)f2bf(v0[i] - bf2f(hb));
        unsigned short hb2 = f2bf(v1[i]);
        ahi[4 + i] = (short)hb2;
        alo[4 + i] = (short)f2bf(v1[i] - bf2f(hb2));
      }
    } else {           // h / hr part: packed hi/lo, coherent loads
      const int k0 = koff - DD;
      const u64* src = (const u64*)(vpack + (size_t)rowb * UU + k0);
      u64 q0 = ld_coh_u64(src + 0);
      u64 q1 = ld_coh_u64(src + 1);
      u64 q2 = ld_coh_u64(src + 2);
      u64 q3 = ld_coh_u64(src + 3);
      u32 w[8] = {(u32)q0, (u32)(q0 >> 32), (u32)q1, (u32)(q1 >> 32),
                  (u32)q2, (u32)(q2 >> 32), (u32)q3, (u32)(q3 >> 32)};
#pragma unroll
      for (int i = 0; i < 8; ++i) {
        ahi[i] = (short)(w[i] >> 16);
        alo[i] = (short)(w[i] & 0xffffu);
      }
    }
    bf16x8 bhi = *(const bf16x8*)(whi_lds + c * WPAD + koff);
    bf16x8 blo = *(const bf16x8*)(wlo_lds + c * WPAD + koff);
    acc = __builtin_amdgcn_mfma_f32_16x16x32_bf16(ahi, bhi, acc, 0, 0, 0);
    acc = __builtin_amdgcn_mfma_f32_16x16x32_bf16(ahi, blo, acc, 0, 0, 0);
    acc = __builtin_amdgcn_mfma_f32_16x16x32_bf16(alo, bhi, acc, 0, 0, 0);
  }
  return acc;
}

__global__ __launch_bounds__(256, 1) void gru_persist(
    const float* __restrict__ x, const float* __restrict__ Wk,
    const float* __restrict__ Wrk, const float* __restrict__ brk,
    const float* __restrict__ Wu, const float* __restrict__ Wur,
    const float* __restrict__ bur, float* __restrict__ out,
    unsigned char* __restrict__ ws) {
  __shared__ unsigned short w1hi[16 * WPAD], w1lo[16 * WPAD];
  __shared__ unsigned short w2hi[16 * WPAD], w2lo[16 * WPAD];
  __shared__ float scratch[4 * 256];

  const int wg = blockIdx.x;
  const int bblk = wg & 3;        // batch block (16 rows)
  const int cblk = wg >> 2;       // 0..63: z cols [cblk*16,+16); if <32 also u cols
  const int tid = threadIdx.x;
  const int lane = tid & 63;
  const int wv = tid >> 6;

  float* zt_f32 = (float*)(ws);
  u32* h_pack = (u32*)(ws + 131072);
  u32* hr_pack = (u32*)(ws + 262144);
  unsigned* ctr = (unsigned*)(ws + 393216) + (size_t)bblk * 64;

  const int C0 = cblk * 16;

  // ---- one-time weight preload into LDS (bf16 hi/lo split, transposed [c][k])
  for (int idx = tid; idx < 16 * K1; idx += 256) {
    int c = idx & 15, k = idx >> 4;
    float v = (k < DD) ? Wk[(size_t)k * 1024 + C0 + c]
                       : Wrk[(size_t)(k - DD) * 1024 + C0 + c];
    unsigned short hb = f2bf(v);
    w1hi[c * WPAD + k] = hb;
    w1lo[c * WPAD + k] = f2bf(v - bf2f(hb));
  }
  if (cblk < 32) {
    for (int idx = tid; idx < 16 * K1; idx += 256) {
      int c = idx & 15, k = idx >> 4;
      float v = (k < DD) ? Wu[(size_t)k * UU + C0 + c]
                         : Wur[(size_t)(k - DD) * UU + C0 + c];
      unsigned short hb = f2bf(v);
      w2hi[c * WPAD + k] = hb;
      w2lo[c * WPAD + k] = f2bf(v - bf2f(hb));
    }
  }
  __syncthreads();

  const int rowb = bblk * 16 + (lane & 15);  // this lane's global batch row
  unsigned bar = 0;

  for (int t = 0; t < TT; ++t) {
    const float* xrow = x + (size_t)rowb * TT * DD + (size_t)t * DD;

    // ---------- phase 1: z tile [16 x 16] for cols C0..C0+15 of 1024
    {
      f32x4 a = tile_gemm(w1hi, w1lo, h_pack, xrow, rowb, wv, lane);
#pragma unroll
      for (int r = 0; r < 4; ++r)
        scratch[wv * 256 + ((lane >> 4) * 4 + r) * 16 + (lane & 15)] = a[r];
      __syncthreads();
      {
        int bl = tid >> 4, cl = tid & 15;
        float z = scratch[tid] + scratch[256 + tid] + scratch[512 + tid] +
                  scratch[768 + tid];
        int Cg = C0 + cl;
        int B = bblk * 16 + bl;
        z += brk[Cg];
        float s = 1.f / (1.f + expf(-z));
        if (Cg < UU) {  // r gate -> h*r, pack hi/lo
          u32 hp = ld_coh_u32(h_pack + (size_t)B * UU + Cg);
          float h = bf2f((unsigned short)(hp >> 16)) +
                    bf2f((unsigned short)(hp & 0xffffu));
          float hrv = h * s;
          unsigned short hb = f2bf(hrv);
          unsigned short lb = f2bf(hrv - bf2f(hb));
          st_coh_u32(hr_pack + (size_t)B * UU + Cg,
                     ((u32)hb << 16) | (u32)lb);
        } else {        // update gate
          st_coh_f32(zt_f32 + (size_t)B * UU + (Cg - UU), s);
        }
      }
    }
    group_barrier(ctr, (++bar) * 64);

    // ---------- phase 2: u tile -> h update (wgs with cblk < 32)
    if (cblk < 32) {
      f32x4 a = tile_gemm(w2hi, w2lo, hr_pack, xrow, rowb, wv, lane);
#pragma unroll
      for (int r = 0; r < 4; ++r)
        scratch[wv * 256 + ((lane >> 4) * 4 + r) * 16 + (lane & 15)] = a[r];
      __syncthreads();
      {
        int bl = tid >> 4, cl = tid & 15;
        float u = scratch[tid] + scratch[256 + tid] + scratch[512 + tid] +
                  scratch[768 + tid];
        int Cu = C0 + cl;
        int B = bblk * 16 + bl;
        u += bur[Cu];
        float ht = tanhf(u);
        float zt = ld_coh_f32(zt_f32 + (size_t)B * UU + Cu);
        u32 hp = ld_coh_u32(h_pack + (size_t)B * UU + Cu);
        float ho = bf2f((unsigned short)(hp >> 16)) +
                   bf2f((unsigned short)(hp & 0xffffu));
        float hn = ho + zt * (ht - ho);
        unsigned short hb = f2bf(hn);
        unsigned short lb = f2bf(hn - bf2f(hb));
        st_coh_u32(h_pack + (size_t)B * UU + Cu, ((u32)hb << 16) | (u32)lb);
        if (t == TT - 1) out[(size_t)B * UU + Cu] = hn;
      }
    }
    group_barrier(ctr, (++bar) * 64);
  }
}

extern "C" void kernel_launch(void* const* d_in, const int* in_sizes, int n_in,
                              void* d_out, int out_size, void* d_ws,
                              size_t ws_size, hipStream_t stream) {
  (void)in_sizes; (void)n_in; (void)out_size; (void)ws_size;
  // zero h state + barrier counters (graph-capturable async memset)
  hipMemsetAsync(d_ws, 0, 394240, stream);
  gru_persist<<<dim3(256), dim3(256), 0, stream>>>(
      (const float*)d_in[0], (const float*)d_in[1], (const float*)d_in[2],
      (const float*)d_in[3], (const float*)d_in[4], (const float*)d_in[5],
      (const float*)d_in[6], (float*)d_out, (unsigned char*)d_ws);
}

// Round 3
// 16408.992 us; speedup vs baseline: 4.1558x; 1.4556x over previous
//
#include <hip/hip_runtime.h>

// BasicGRU persistent kernel for MI355X (gfx950) — round 3.
//
//  - 256 wgs x 256 thr, 1 wg/CU (96KB LDS pad). 4 batch groups x 64 wgs.
//  - RMW-free flag barrier: each wg stores its own monotonically-increasing
//    arrival counter (coherent, 16B-spread); wave 0 polls all 64 flags with a
//    64-lane gather + __all. No same-line atomic-add convoy.
//  - Weights live in VGPRs as bf16 hi/lo split fragments (loaded once).
//    LDS only holds the 4-wave reduce scratch (+pad to pin 1 wg/CU).
//  - x_t fragments pre-split into registers during the barrier-2 wait of the
//    previous step (phase 1 and 2 share the same x fragments).
//  - h / h*r cross-wg state: packed u32 (bf16hi<<16|bf16lo) in ws, relaxed
//    agent-scope (sc0 sc1) loads/stores only — no cache maintenance anywhere.
//  - Column remap: wg cb<32 ("r-wg") does r-gate cols [cb*16,+16) in phase 1;
//    wg cb>=32 ("z-wg") does update-gate cols 512+(cb-32)*16 in phase 1 and
//    u cols (cb-32)*16 in phase 2 -> z_t gate stays in registers.
//
// ws: h_pack [64][512] u32 @0; hr_pack @131072; flags @262144 (4 grp x 1KB).

#define TT 2048
#define DD 256
#define UU 512

typedef short bf16x8 __attribute__((ext_vector_type(8)));
typedef float f32x4 __attribute__((ext_vector_type(4)));
typedef unsigned int u32;
typedef unsigned long long u64;

#define H_OFF 0
#define HR_OFF 131072
#define FLAG_OFF 262144
#define WS_BYTES 266240

__device__ inline unsigned short f2bf(float f) {
  unsigned u = __builtin_bit_cast(unsigned, f);
  u += 0x7FFFu + ((u >> 16) & 1u);  // round-nearest-even
  return (unsigned short)(u >> 16);
}
__device__ inline float bf2f(unsigned short b) {
  unsigned u = ((unsigned)b) << 16;
  return __builtin_bit_cast(float, u);
}
__device__ inline u32 ld_coh_u32(const u32* p) {
  return __hip_atomic_load(p, __ATOMIC_RELAXED, __HIP_MEMORY_SCOPE_AGENT);
}
__device__ inline u64 ld_coh_u64(const u64* p) {
  return __hip_atomic_load(p, __ATOMIC_RELAXED, __HIP_MEMORY_SCOPE_AGENT);
}
__device__ inline void st_coh_u32(u32* p, u32 v) {
  __hip_atomic_store(p, v, __ATOMIC_RELAXED, __HIP_MEMORY_SCOPE_AGENT);
}

#define MFMA(A, B, C) __builtin_amdgcn_mfma_f32_16x16x32_bf16((A), (B), (C), 0, 0, 0)

__global__ __launch_bounds__(256, 1) void gru_persist(
    const float* __restrict__ x, const float* __restrict__ Wk,
    const float* __restrict__ Wrk, const float* __restrict__ brk,
    const float* __restrict__ Wu, const float* __restrict__ Wur,
    const float* __restrict__ bur, float* __restrict__ out,
    unsigned char* __restrict__ ws) {
  __shared__ float scratch[24576];  // 96 KiB: [0,1024) used, rest pins 1 wg/CU

  const int wg = blockIdx.x;
  const int bblk = wg & 3;          // batch group (16 rows)
  const int cb = wg >> 2;           // 0..63
  const bool zwg = (cb >= 32);
  const int tid = threadIdx.x;
  const int lane = tid & 63;
  const int wv = tid >> 6;
  const int kgrp = lane >> 4;
  const int c = lane & 15;

  const int P1C0 = cb * 16;                   // phase-1 col base in [0,1024)
  const int P2C0 = zwg ? (cb - 32) * 16 : 0;  // phase-2 u col base

  u32* h_pack = (u32*)(ws + H_OFF);
  u32* hr_pack = (u32*)(ws + HR_OFF);
  u32* flags = (u32*)(ws + FLAG_OFF) + bblk * 256;  // 64 slots x 4 u32 (16B)

  // ---- one-time: weight B-fragments -> registers (bf16 hi/lo split).
  // Wave wv owns K-chunks gc = wv + 4j, j=0..5 (j<2 are x-rows, j>=2 h-rows).
  bf16x8 w1hi[6], w1lo[6], w2hi[6], w2lo[6];
#pragma unroll
  for (int j = 0; j < 6; ++j) {
    const int kb = (wv + 4 * j) * 32 + kgrp * 8;
#pragma unroll
    for (int i = 0; i < 8; ++i) {
      const int k = kb + i;
      float v = (k < DD) ? Wk[(size_t)k * 1024 + P1C0 + c]
                         : Wrk[(size_t)(k - DD) * 1024 + P1C0 + c];
      unsigned short hb = f2bf(v);
      w1hi[j][i] = (short)hb;
      w1lo[j][i] = (short)f2bf(v - bf2f(hb));
      float v2 = 0.f;
      if (zwg)
        v2 = (k < DD) ? Wu[(size_t)k * UU + P2C0 + c]
                      : Wur[(size_t)(k - DD) * UU + P2C0 + c];
      unsigned short hb2 = f2bf(v2);
      w2hi[j][i] = (short)hb2;
      w2lo[j][i] = (short)f2bf(v2 - bf2f(hb2));
    }
  }

  const int bl = tid >> 4, cl = tid & 15;  // reduce-thread coords
  const int Bg = bblk * 16 + bl;
  const float b1 = brk[P1C0 + cl];
  const float b2 = zwg ? bur[P2C0 + cl] : 0.f;

  const int rowb = bblk * 16 + c;  // A-operand batch row for this lane

  // x fragments for the current step (shared by both phases).
  bf16x8 xhi[2], xlo[2];
  auto split_x = [&](int t) {
#pragma unroll
    for (int j = 0; j < 2; ++j) {
      const float* xr =
          x + ((size_t)rowb * TT + t) * DD + wv * 32 + j * 128 + kgrp * 8;
      f32x4 v0 = *(const f32x4*)(xr);
      f32x4 v1 = *(const f32x4*)(xr + 4);
#pragma unroll
      for (int i = 0; i < 4; ++i) {
        unsigned short hb = f2bf(v0[i]);
        xhi[j][i] = (short)hb;
        xlo[j][i] = (short)f2bf(v0[i] - bf2f(hb));
        unsigned short hb2 = f2bf(v1[i]);
        xhi[j][4 + i] = (short)hb2;
        xlo[j][4 + i] = (short)f2bf(v1[i] - bf2f(hb2));
      }
    }
  };
  split_x(0);

  // 16-col z/u tile K-partial: x chunks from regs, h/hr chunks coherent.
  auto gemm = [&](const u32* pack, const bf16x8* whi,
                  const bf16x8* wlo) -> f32x4 {
    u64 q[4][4];  // issue ALL coherent loads first (one L3 latency, pipelined)
#pragma unroll
    for (int j = 0; j < 4; ++j) {
      const int k0 = wv * 32 + j * 128 + kgrp * 8;
      const u64* src = (const u64*)(pack + (size_t)rowb * UU + k0);
      q[j][0] = ld_coh_u64(src + 0);
      q[j][1] = ld_coh_u64(src + 1);
      q[j][2] = ld_coh_u64(src + 2);
      q[j][3] = ld_coh_u64(src + 3);
    }
    f32x4 a0 = {0.f, 0.f, 0.f, 0.f}, a1 = {0.f, 0.f, 0.f, 0.f};
    a0 = MFMA(xhi[0], whi[0], a0);
    a0 = MFMA(xhi[0], wlo[0], a0);
    a0 = MFMA(xlo[0], whi[0], a0);
    a1 = MFMA(xhi[1], whi[1], a1);
    a1 = MFMA(xhi[1], wlo[1], a1);
    a1 = MFMA(xlo[1], whi[1], a1);
#pragma unroll
    for (int j = 0; j < 4; ++j) {
      bf16x8 ahi, alo;
#pragma unroll
      for (int i = 0; i < 4; ++i) {
        u32 lo32 = (u32)q[j][i];
        u32 hi32 = (u32)(q[j][i] >> 32);
        ahi[2 * i] = (short)(lo32 >> 16);
        alo[2 * i] = (short)lo32;
        ahi[2 * i + 1] = (short)(hi32 >> 16);
        alo[2 * i + 1] = (short)hi32;
      }
      if ((j & 1) == 0) {
        a0 = MFMA(ahi, whi[j + 2], a0);
        a0 = MFMA(ahi, wlo[j + 2], a0);
        a0 = MFMA(alo, whi[j + 2], a0);
      } else {
        a1 = MFMA(ahi, whi[j + 2], a1);
        a1 = MFMA(ahi, wlo[j + 2], a1);
        a1 = MFMA(alo, whi[j + 2], a1);
      }
    }
    return a0 + a1;
  };

  unsigned bar = 0;
  for (int t = 0; t < TT; ++t) {
    // ================= phase 1: z = [x|h] @ [Wk;Wrk] + brk (all wgs)
    u32 hp = 0;
    if (!zwg) hp = ld_coh_u32(h_pack + (size_t)Bg * UU + P1C0 + cl);  // prefetch
    f32x4 acc = gemm(h_pack, w1hi, w1lo);
#pragma unroll
    for (int r = 0; r < 4; ++r)
      scratch[wv * 256 + (kgrp * 4 + r) * 16 + c] = acc[r];
    __syncthreads();
    {
      float z = (scratch[tid] + scratch[256 + tid]) +
                (scratch[512 + tid] + scratch[768 + tid]) + b1;
      float s = 1.f / (1.f + __expf(-z));
      if (!zwg) {  // r gate -> hr = h*r, packed coherent store
        float h = bf2f((unsigned short)(hp >> 16)) + bf2f((unsigned short)hp);
        float hrv = h * s;
        unsigned short hb = f2bf(hrv);
        unsigned short lb = f2bf(hrv - bf2f(hb));
        st_coh_u32(hr_pack + (size_t)Bg * UU + P1C0 + cl,
                   ((u32)hb << 16) | lb);
      }
      // z-wg: update gate stays in register
      float zt = s;

      // ---- barrier 1 (flags, no RMW)
      asm volatile("s_waitcnt vmcnt(0)" ::: "memory");
      __syncthreads();
      ++bar;
      if (tid == 0) st_coh_u32(flags + cb * 4, bar);
      if (wv == 0) {
        const u32* fp = flags + lane * 4;
        while (!__all(ld_coh_u32(fp) >= bar)) {
        }
      }
      __syncthreads();

      // ================= phase 2: u = [x|hr] @ [Wu;Wur] + bur (z-wgs)
      if (zwg) {
        u32 hp2 = ld_coh_u32(h_pack + (size_t)Bg * UU + P2C0 + cl);
        f32x4 acc2 = gemm(hr_pack, w2hi, w2lo);
#pragma unroll
        for (int r = 0; r < 4; ++r)
          scratch[wv * 256 + (kgrp * 4 + r) * 16 + c] = acc2[r];
        __syncthreads();
        float u = (scratch[tid] + scratch[256 + tid]) +
                  (scratch[512 + tid] + scratch[768 + tid]) + b2;
        float e = __expf(2.f * u);
        float ht = 1.f - 2.f / (e + 1.f);  // tanh(u)
        float ho = bf2f((unsigned short)(hp2 >> 16)) + bf2f((unsigned short)hp2);
        float hn = ho + zt * (ht - ho);
        unsigned short hb = f2bf(hn);
        unsigned short lb = f2bf(hn - bf2f(hb));
        st_coh_u32(h_pack + (size_t)Bg * UU + P2C0 + cl, ((u32)hb << 16) | lb);
        if (t == TT - 1) out[(size_t)Bg * UU + P2C0 + cl] = hn;
      }

      // ---- barrier 2 + x prefetch/split for t+1 (hidden under the wait)
      asm volatile("s_waitcnt vmcnt(0)" ::: "memory");
      __syncthreads();
      ++bar;
      if (tid == 0) st_coh_u32(flags + cb * 4, bar);
      if (t + 1 < TT) split_x(t + 1);
      if (wv == 0) {
        const u32* fp = flags + lane * 4;
        while (!__all(ld_coh_u32(fp) >= bar)) {
        }
      }
      __syncthreads();
    }
  }
}

extern "C" void kernel_launch(void* const* d_in, const int* in_sizes, int n_in,
                              void* d_out, int out_size, void* d_ws,
                              size_t ws_size, hipStream_t stream) {
  (void)in_sizes; (void)n_in; (void)out_size; (void)ws_size;
  hipMemsetAsync(d_ws, 0, WS_BYTES, stream);  // h0 = 0, flags = 0
  gru_persist<<<dim3(256), dim3(256), 0, stream>>>(
      (const float*)d_in[0], (const float*)d_in[1], (const float*)d_in[2],
      (const float*)d_in[3], (const float*)d_in[4], (const float*)d_in[5],
      (const float*)d_in[6], (float*)d_out, (unsigned char*)d_ws);
}